// Round 4
// baseline (452.266 us; speedup 1.0000x reference)
//
#include <hip/hip_runtime.h>
#include <hip/hip_bf16.h>

#define BB 32
#define CC 256
#define CQK 32
#define LL 1024
#define OTOT 320

// ---------------- workspace layout ----------------
// float region:
#define WCAT_OFF 0
#define BCAT_OFF (OTOT * CC)                 // 81920
#define QK_OFF   (BCAT_OFF + OTOT)           // 82240
#define QK_SIZE  (BB * 64 * LL)              // 2097152
#define US_BASE  (QK_OFF + QK_SIZE)          // 2179392 floats (byte 8717568, 16B aligned)
// ushort region (offsets in ushorts from US_BASE):
#define VBF_OFF   ((size_t)0)
#define WVBF_OFF  ((size_t)BB * CC * LL)                  // 8388608
#define XT_OFF    (WVBF_OFF + (size_t)CC * CC)
#define KTH_OFF   (XT_OFF + (size_t)BB * LL * CC)
#define KTL_OFF   (KTH_OFF + (size_t)BB * LL * 32)

typedef __bf16 bf16x8 __attribute__((ext_vector_type(8)));
typedef float f32x4 __attribute__((ext_vector_type(4)));

__device__ inline void async_ld16(const void* g, void* l) {
  __builtin_amdgcn_global_load_lds(
      (const __attribute__((address_space(1))) void*)g,
      (__attribute__((address_space(3))) void*)l, 16, 0, 0);
}

__device__ inline ushort f2bu(float f) {
  union { __hip_bfloat16 h; ushort u; } c;
  c.h = __float2bfloat16(f);
  return c.u;
}
__device__ inline float bu2f(ushort u) {
  union { __hip_bfloat16 h; ushort u; } c;
  c.u = u;
  return __bfloat162float(c.h);
}

// ---------------------------------------------------------------- pack W+b
__global__ __launch_bounds__(256) void pack_w_kernel(
    const float* __restrict__ Wq, const float* __restrict__ bq,
    const float* __restrict__ Wk, const float* __restrict__ bk,
    const float* __restrict__ Wv, const float* __restrict__ bv,
    float* __restrict__ Wcat, float* __restrict__ bcat,
    ushort* __restrict__ Wvbf) {
  int o = blockIdx.x;
  int c = threadIdx.x;
  float w = (o < CQK) ? Wq[o * CC + c]
          : (o < 2 * CQK) ? Wk[(o - CQK) * CC + c]
          : Wv[(o - 2 * CQK) * CC + c];
  Wcat[o * CC + c] = w;
  if (o >= 64) Wvbf[(o - 64) * CC + c] = f2bu(w);
  if (c == 0) {
    bcat[o] = (o < CQK) ? bq[o] : (o < 2 * CQK) ? bk[o - CQK] : bv[o - 2 * CQK];
  }
}

// ------------------- q/k projection (fp32 VALU) + xT bf16 emission
#define PPITCH 68
__global__ __launch_bounds__(256) void proj_qk_xt_kernel(
    const float* __restrict__ x, const float* __restrict__ Wcat,
    const float* __restrict__ bcat, float* __restrict__ qk,
    ushort* __restrict__ xT) {
  __shared__ float ws[32][PPITCH];
  __shared__ float xs[32][PPITCH];
  int b = blockIdx.z;
  int l0 = blockIdx.x * 64;
  int tid = threadIdx.x;
  int tx = tid & 15, ty = tid >> 4;
  const float* xb = x + (size_t)b * CC * LL;
  ushort* xTb = xT + (size_t)b * LL * CC;
  float acc[4][4] = {};

  for (int c0 = 0; c0 < CC; c0 += 32) {
    __syncthreads();
    {
      int o = tid >> 5;
      int kk = tid & 31;
#pragma unroll
      for (int r = 0; r < 8; ++r)
        ws[kk][o + 8 * r] = Wcat[(o + 8 * r) * CC + c0 + kk];
      int l = tid & 63;
      int k4 = tid >> 6;
#pragma unroll
      for (int r = 0; r < 8; ++r)
        xs[k4 + 4 * r][l] = xb[(size_t)(c0 + k4 + 4 * r) * LL + l0 + l];
    }
    __syncthreads();
#pragma unroll 8
    for (int kk = 0; kk < 32; ++kk) {
      float a[4], bvv[4];
      *(float4*)a = *(const float4*)&ws[kk][ty * 4];
      *(float4*)bvv = *(const float4*)&xs[kk][tx * 4];
#pragma unroll
      for (int i = 0; i < 4; ++i)
#pragma unroll
        for (int j = 0; j < 4; ++j)
          acc[i][j] = fmaf(a[i], bvv[j], acc[i][j]);
    }
    // emit xT bf16 for this (c0..c0+32, l0..l0+64) tile
    {
      int l = tid >> 2;            // 0..63
      int c8 = (tid & 3) * 8;      // 0,8,16,24
      ushort u[8];
#pragma unroll
      for (int j = 0; j < 8; ++j) u[j] = f2bu(xs[c8 + j][l]);
      *(ushort4*)&xTb[(size_t)(l0 + l) * CC + c0 + c8] = *(ushort4*)&u[0];
      *(ushort4*)&xTb[(size_t)(l0 + l) * CC + c0 + c8 + 4] = *(ushort4*)&u[4];
    }
  }
#pragma unroll
  for (int i = 0; i < 4; ++i) {
    int o = ty * 4 + i;
    float bias = bcat[o];
    float4 r;
    r.x = acc[i][0] + bias;
    r.y = acc[i][1] + bias;
    r.z = acc[i][2] + bias;
    r.w = acc[i][3] + bias;
    *(float4*)&qk[((size_t)b * 64 + o) * LL + l0 + tx * 4] = r;
  }
}

// ---------------- pack k rows into B-fragment order, hi/lo bf16
__global__ __launch_bounds__(256) void kT_pack_kernel(
    const float* __restrict__ qk, ushort* __restrict__ kth,
    ushort* __restrict__ ktl) {
  __shared__ float ks[32][257];
  int b = blockIdx.y, jg = blockIdx.x;  // col group of 256
  int tid = threadIdx.x;
  const float* kb = qk + ((size_t)b * 64 + CQK) * LL + jg * 256;
#pragma unroll
  for (int i = 0; i < 8; ++i) {
    int row = i * 4 + (tid >> 6);
    int col4 = (tid & 63) * 4;
    float4 v = *(const float4*)&kb[(size_t)row * LL + col4];
    ks[row][col4 + 0] = v.x;
    ks[row][col4 + 1] = v.y;
    ks[row][col4 + 2] = v.z;
    ks[row][col4 + 3] = v.w;
  }
  __syncthreads();
#pragma unroll
  for (int rep = 0; rep < 4; ++rep) {
    int idx = rep * 256 + tid;
    int jt_l = idx >> 6;
    int q = (idx >> 4) & 3;
    int l16 = idx & 15;
    ushort h[8], lo[8];
#pragma unroll
    for (int jj = 0; jj < 8; ++jj) {
      float v = ks[q * 8 + jj][jt_l * 16 + l16];
      ushort hh = f2bu(v);
      h[jj] = hh;
      lo[jj] = f2bu(v - bu2f(hh));
    }
    size_t off = (((size_t)b * 64 + jg * 16 + jt_l) * 64 + (idx & 63)) * 8;
    *(ushort4*)&kth[off] = *(ushort4*)&h[0];
    *(ushort4*)&kth[off + 4] = *(ushort4*)&h[4];
    *(ushort4*)&ktl[off] = *(ushort4*)&lo[0];
    *(ushort4*)&ktl[off + 4] = *(ushort4*)&lo[4];
  }
}

// ---------------- v projection: vbf[b][c][l] = bf16( Wv·x + bv ), MFMA
__global__ __launch_bounds__(256) void v_mfma_kernel(
    const ushort* __restrict__ Wvbf, const ushort* __restrict__ xT,
    const float* __restrict__ bv, ushort* __restrict__ vbf) {
  __shared__ ushort As[128 * 32];
  __shared__ ushort Bs[128 * 32];
  int b = blockIdx.z;
  int c0 = blockIdx.y * 128;
  int l0 = blockIdx.x * 128;
  int tid = threadIdx.x;
  int wave = tid >> 6, lane = tid & 63;
  int quad = lane >> 4, ln = lane & 15;
  int wr = (wave >> 1) * 64;
  int wc = (wave & 1) * 64;
  const ushort* xb = xT + (size_t)b * LL * CC;
  int r0 = tid >> 2, r1 = r0 + 64;
  int cq = (tid & 3) * 8;
  ushort* lA0 = As + (size_t)(wave * 64) * 8;
  ushort* lA1 = As + (size_t)(256 + wave * 64) * 8;
  ushort* lB0 = Bs + (size_t)(wave * 64) * 8;
  ushort* lB1 = Bs + (size_t)(256 + wave * 64) * 8;

  f32x4 acc[4][4];
#pragma unroll
  for (int i = 0; i < 4; ++i)
#pragma unroll
    for (int j = 0; j < 4; ++j) acc[i][j] = {0.f, 0.f, 0.f, 0.f};

  for (int kt = 0; kt < CC; kt += 32) {
    __syncthreads();
    async_ld16(Wvbf + (size_t)(c0 + r0) * CC + kt + cq, lA0);
    async_ld16(Wvbf + (size_t)(c0 + r1) * CC + kt + cq, lA1);
    async_ld16(xb + (size_t)(l0 + r0) * CC + kt + cq, lB0);
    async_ld16(xb + (size_t)(l0 + r1) * CC + kt + cq, lB1);
    __syncthreads();
    bf16x8 af[4], bfr[4];
#pragma unroll
    for (int i = 0; i < 4; ++i)
      af[i] = *(const bf16x8*)&As[(size_t)(wr + i * 16 + ln) * 32 + quad * 8];
#pragma unroll
    for (int j = 0; j < 4; ++j)
      bfr[j] = *(const bf16x8*)&Bs[(size_t)(wc + j * 16 + ln) * 32 + quad * 8];
#pragma unroll
    for (int i = 0; i < 4; ++i)
#pragma unroll
      for (int j = 0; j < 4; ++j)
        acc[i][j] = __builtin_amdgcn_mfma_f32_16x16x32_bf16(af[i], bfr[j], acc[i][j], 0, 0, 0);
  }

  ushort* vb = vbf + (size_t)b * CC * LL;
#pragma unroll
  for (int i = 0; i < 4; ++i) {
#pragma unroll
    for (int r = 0; r < 4; ++r) {
      int c = c0 + wr + i * 16 + quad * 4 + r;
      float bias = bv[c];
#pragma unroll
      for (int j = 0; j < 4; ++j) {
        int l = l0 + wc + j * 16 + ln;
        vb[(size_t)c * LL + l] = f2bu(acc[i][j][r] + bias);
      }
    }
  }
}

// ================= fused: scores (hi/lo MFMA) + softmax + att store +
//                   PV GEMM (out = gamma*V.P^T + x)
// block: 32 att rows x 1024 cols; wave w owns score cols [w*256, w*256+256)
// PV: wave w owns out rows c in [w*64, w*64+64)
__global__ __launch_bounds__(256, 2) void attn_fused_kernel(
    const float* __restrict__ qk, const ushort* __restrict__ kth,
    const ushort* __restrict__ ktl, const ushort* __restrict__ vbf,
    const float* __restrict__ x, const float* __restrict__ gamma,
    float* __restrict__ att, float* __restrict__ out) {
  __shared__ float qs[32][33];          // [d][row]
  __shared__ ushort P2[32 * 32 * 32];   // [ktile][row][k] 64 KB
  __shared__ float red[4][32];
  int b = blockIdx.y;
  int i0 = blockIdx.x * 32;
  int tid = threadIdx.x;
  int wave = tid >> 6, lane = tid & 63;
  int quad = lane >> 4, ln = lane & 15;

  // ---- stage q tile [32 d][32 rows]
  const float* qb = qk + (size_t)b * 64 * LL;
  {
    int d = tid >> 3, c4 = (tid & 7) * 4;
    float4 v = *(const float4*)&qb[(size_t)d * LL + i0 + c4];
    qs[d][c4 + 0] = v.x;
    qs[d][c4 + 1] = v.y;
    qs[d][c4 + 2] = v.z;
    qs[d][c4 + 3] = v.w;
  }
  __syncthreads();

  // ---- A fragments hi/lo for mi=0,1: A[m=mi*16+ln][k=quad*8+jj]
  bf16x8 ahi[2], alo[2];
#pragma unroll
  for (int mi = 0; mi < 2; ++mi) {
    union { bf16x8 v; ushort u[8]; } H, L;
#pragma unroll
    for (int jj = 0; jj < 8; ++jj) {
      float v = qs[quad * 8 + jj][mi * 16 + ln];
      ushort hh = f2bu(v);
      H.u[jj] = hh;
      L.u[jj] = f2bu(v - bu2f(hh));
    }
    ahi[mi] = H.v;
    alo[mi] = L.v;
  }

  // ---- scores: direct global B-frag loads (packed layout)
  const ushort* khB = kth + (size_t)b * LL * 32;
  const ushort* klB = ktl + (size_t)b * LL * 32;
  f32x4 acc[2][16];
#pragma unroll
  for (int mi = 0; mi < 2; ++mi)
#pragma unroll
    for (int f = 0; f < 16; ++f) acc[mi][f] = {0.f, 0.f, 0.f, 0.f};

#pragma unroll 4
  for (int f = 0; f < 16; ++f) {
    size_t off = (((size_t)(wave * 16 + f)) * 64 + lane) * 8;
    bf16x8 bh = *(const bf16x8*)&khB[off];
    bf16x8 bl = *(const bf16x8*)&klB[off];
#pragma unroll
    for (int mi = 0; mi < 2; ++mi) {
      acc[mi][f] = __builtin_amdgcn_mfma_f32_16x16x32_bf16(ahi[mi], bh, acc[mi][f], 0, 0, 0);
      acc[mi][f] = __builtin_amdgcn_mfma_f32_16x16x32_bf16(ahi[mi], bl, acc[mi][f], 0, 0, 0);
      acc[mi][f] = __builtin_amdgcn_mfma_f32_16x16x32_bf16(alo[mi], bh, acc[mi][f], 0, 0, 0);
    }
  }

  // ---- row max (within wave: over f and 16 lanes of ln)
  float mrow[2][4];
#pragma unroll
  for (int mi = 0; mi < 2; ++mi)
#pragma unroll
    for (int r = 0; r < 4; ++r) {
      float m = acc[mi][0][r];
#pragma unroll
      for (int f = 1; f < 16; ++f) m = fmaxf(m, acc[mi][f][r]);
      mrow[mi][r] = m;
    }
#pragma unroll
  for (int mask = 1; mask < 16; mask <<= 1)
#pragma unroll
    for (int mi = 0; mi < 2; ++mi)
#pragma unroll
      for (int r = 0; r < 4; ++r)
        mrow[mi][r] = fmaxf(mrow[mi][r], __shfl_xor(mrow[mi][r], mask));
  if (ln == 0) {
#pragma unroll
    for (int mi = 0; mi < 2; ++mi)
#pragma unroll
      for (int r = 0; r < 4; ++r)
        red[wave][mi * 16 + quad * 4 + r] = mrow[mi][r];
  }
  __syncthreads();
  float gmax[2][4];
#pragma unroll
  for (int mi = 0; mi < 2; ++mi)
#pragma unroll
    for (int r = 0; r < 4; ++r) {
      int row = mi * 16 + quad * 4 + r;
      gmax[mi][r] = fmaxf(fmaxf(red[0][row], red[1][row]),
                          fmaxf(red[2][row], red[3][row]));
    }
  __syncthreads();

  // ---- exp + row sum
  float ssum[2][4] = {};
#pragma unroll
  for (int mi = 0; mi < 2; ++mi)
#pragma unroll
    for (int f = 0; f < 16; ++f)
#pragma unroll
      for (int r = 0; r < 4; ++r) {
        float e = __expf(acc[mi][f][r] - gmax[mi][r]);
        acc[mi][f][r] = e;
        ssum[mi][r] += e;
      }
#pragma unroll
  for (int mask = 1; mask < 16; mask <<= 1)
#pragma unroll
    for (int mi = 0; mi < 2; ++mi)
#pragma unroll
      for (int r = 0; r < 4; ++r) ssum[mi][r] += __shfl_xor(ssum[mi][r], mask);
  if (ln == 0) {
#pragma unroll
    for (int mi = 0; mi < 2; ++mi)
#pragma unroll
      for (int r = 0; r < 4; ++r)
        red[wave][mi * 16 + quad * 4 + r] = ssum[mi][r];
  }
  __syncthreads();
  float inv[2][4];
#pragma unroll
  for (int mi = 0; mi < 2; ++mi)
#pragma unroll
    for (int r = 0; r < 4; ++r) {
      int row = mi * 16 + quad * 4 + r;
      inv[mi][r] = 1.0f / (red[0][row] + red[1][row] + red[2][row] + red[3][row]);
    }

  // ---- normalize; store att fp32; store P bf16 to LDS [ktile][row][k]
  float* attB = att + (size_t)b * LL * LL;
#pragma unroll
  for (int mi = 0; mi < 2; ++mi)
#pragma unroll
    for (int r = 0; r < 4; ++r) {
      int row = mi * 16 + quad * 4 + r;
      size_t ro = (size_t)(i0 + row) * LL;
#pragma unroll
      for (int f = 0; f < 16; ++f) {
        int col = wave * 256 + f * 16 + ln;
        float p = acc[mi][f][r] * inv[mi][r];
        attB[ro + col] = p;
        P2[((col >> 5) * 32 + row) * 32 + (col & 31)] = f2bu(p);
      }
    }
  __syncthreads();

  // ---- PV: out rows c in [wave*64, wave*64+64), K = 1024
  const ushort* vb = vbf + (size_t)b * CC * LL;
  f32x4 o[4][2];
#pragma unroll
  for (int i = 0; i < 4; ++i) {
    o[i][0] = {0.f, 0.f, 0.f, 0.f};
    o[i][1] = {0.f, 0.f, 0.f, 0.f};
  }
#pragma unroll 4
  for (int kt = 0; kt < 32; ++kt) {
    bf16x8 bf0 = *(const bf16x8*)&P2[((size_t)kt * 32 + ln) * 32 + quad * 8];
    bf16x8 bf1 = *(const bf16x8*)&P2[((size_t)kt * 32 + 16 + ln) * 32 + quad * 8];
#pragma unroll
    for (int i = 0; i < 4; ++i) {
      bf16x8 af = *(const bf16x8*)&vb[(size_t)(wave * 64 + i * 16 + ln) * LL + kt * 32 + quad * 8];
      o[i][0] = __builtin_amdgcn_mfma_f32_16x16x32_bf16(af, bf0, o[i][0], 0, 0, 0);
      o[i][1] = __builtin_amdgcn_mfma_f32_16x16x32_bf16(af, bf1, o[i][1], 0, 0, 0);
    }
  }

  // ---- epilogue: out = gamma * o + x
  float g = gamma[0];
  const float* xb = x + (size_t)b * CC * LL;
  float* ob = out + (size_t)b * CC * LL;
#pragma unroll
  for (int i = 0; i < 4; ++i) {
#pragma unroll
    for (int r = 0; r < 4; ++r) {
      int c = wave * 64 + i * 16 + quad * 4 + r;
#pragma unroll
      for (int nt = 0; nt < 2; ++nt) {
        int m = i0 + nt * 16 + ln;
        size_t idx = (size_t)c * LL + m;
        ob[idx] = fmaf(g, o[i][nt][r], xb[idx]);
      }
    }
  }
}

extern "C" void kernel_launch(void* const* d_in, const int* in_sizes, int n_in,
                              void* d_out, int out_size, void* d_ws, size_t ws_size,
                              hipStream_t stream) {
  const float* x = (const float*)d_in[0];
  const float* Wq = (const float*)d_in[1];
  const float* bq = (const float*)d_in[2];
  const float* Wk = (const float*)d_in[3];
  const float* bk = (const float*)d_in[4];
  const float* Wv = (const float*)d_in[5];
  const float* bv = (const float*)d_in[6];
  const float* gamma = (const float*)d_in[7];

  float* out = (float*)d_out;
  float* att = out + (size_t)BB * CC * LL;

  float* wsf = (float*)d_ws;
  float* Wcat = wsf + WCAT_OFF;
  float* bcat = wsf + BCAT_OFF;
  float* qk = wsf + QK_OFF;
  ushort* usbase = (ushort*)(wsf + US_BASE);
  ushort* vbf = usbase + VBF_OFF;
  ushort* Wvbf = usbase + WVBF_OFF;
  ushort* xT = usbase + XT_OFF;
  ushort* kth = usbase + KTH_OFF;
  ushort* ktl = usbase + KTL_OFF;

  pack_w_kernel<<<dim3(OTOT), dim3(CC), 0, stream>>>(Wq, bq, Wk, bk, Wv, bv, Wcat, bcat, Wvbf);
  proj_qk_xt_kernel<<<dim3(LL / 64, 1, BB), dim3(256), 0, stream>>>(x, Wcat, bcat, qk, xT);
  kT_pack_kernel<<<dim3(4, BB), dim3(256), 0, stream>>>(qk, kth, ktl);
  v_mfma_kernel<<<dim3(LL / 128, CC / 128, BB), dim3(256), 0, stream>>>(Wvbf, xT, bv, vbf);
  attn_fused_kernel<<<dim3(LL / 32, BB), dim3(256), 0, stream>>>(qk, kth, ktl, vbf, x, gamma, att, out);
}